// Round 1
// baseline (9180.524 us; speedup 1.0000x reference)
//
#include <hip/hip_runtime.h>

// LSTM: T=512, B=128, I=256, H=1024.
// Strategy: per-timestep fused GEMM (K = I+H = 1280) with bf16 MFMA 16x16x32.
//   gates[b][n] = sum_k A[b][k] * W[n][k] + bias   (A = [x_t | h_{t-1}])
// Grid per step: 2 row-groups x 128 col-groups = 256 blocks (1 per CU).
// Block: 256 threads, tile 64 rows x 32 gate cols (8 hidden units x 4 gates).
// ws: W_bf16 fused [4096][1280] (10.0 MB) + bias sum (16 KB) + h ping-pong bf16
//     (512 KB) + c state f32 (512 KB)  => ~11.6 MB total.

#define T_STEPS 512
#define BATCH   128
#define IN_DIM  256
#define HID     1024
#define GATES   4096   // 4*HID
#define KDIM    1280   // IN_DIM + HID

typedef __bf16 bf16x8 __attribute__((ext_vector_type(8)));
typedef float  f32x4  __attribute__((ext_vector_type(4)));

__device__ __forceinline__ unsigned short f2bf(float f) {
  unsigned int u = __builtin_bit_cast(unsigned int, f);
  unsigned int r = (u + 0x7FFFu + ((u >> 16) & 1u)) >> 16;  // RNE
  return (unsigned short)r;
}

// W_ih [4096x256] + W_hh [4096x1024] f32 -> fused W_bf [4096][1280] bf16
__global__ void cast_weights(const float* __restrict__ Wih,
                             const float* __restrict__ Whh,
                             unsigned short* __restrict__ Wbf) {
  int gid = blockIdx.x * blockDim.x + threadIdx.x;  // over 4096 * 320 groups of 4
  if (gid >= GATES * (KDIM / 4)) return;
  int n  = gid / (KDIM / 4);
  int k4 = (gid % (KDIM / 4)) * 4;
  float4 v;
  if (k4 < IN_DIM) v = *reinterpret_cast<const float4*>(Wih + (size_t)n * IN_DIM + k4);
  else             v = *reinterpret_cast<const float4*>(Whh + (size_t)n * HID + (k4 - IN_DIM));
  ushort4 o;
  o.x = f2bf(v.x); o.y = f2bf(v.y); o.z = f2bf(v.z); o.w = f2bf(v.w);
  *reinterpret_cast<ushort4*>(Wbf + (size_t)n * KDIM + k4) = o;
}

__global__ void init_state(const float* __restrict__ h0, const float* __restrict__ c0,
                           const float* __restrict__ bih, const float* __restrict__ bhh,
                           unsigned short* __restrict__ hbf0, float* __restrict__ cws,
                           float* __restrict__ bsum) {
  int i = blockIdx.x * blockDim.x + threadIdx.x;
  if (i < BATCH * HID) { hbf0[i] = f2bf(h0[i]); cws[i] = c0[i]; }
  if (i < GATES) bsum[i] = bih[i] + bhh[i];
}

__global__ __launch_bounds__(256) void lstm_step(
    const float* __restrict__ x_t,              // [BATCH][IN_DIM] slice for this t
    const unsigned short* __restrict__ Wbf,     // [GATES][KDIM] bf16
    const float* __restrict__ bsum,             // [GATES]
    const unsigned short* __restrict__ h_in,    // [BATCH][HID] bf16
    unsigned short* __restrict__ h_out,         // [BATCH][HID] bf16
    float* __restrict__ c_ws,                   // [BATCH][HID] f32
    float* __restrict__ out_t)                  // [BATCH][HID] f32 output slice
{
  __shared__ __align__(16) unsigned short As[64][72];  // 64 rows x 64 k (+8 pad)
  __shared__ __align__(16) unsigned short Bs[32][72];  // 32 gate cols x 64 k (+8 pad)
  __shared__ __align__(16) float Gs[64][36];           // gate values for epilogue

  const int tid  = threadIdx.x;
  const int cg   = blockIdx.x;          // 0..127: hidden-column group (8 j's)
  const int rg   = blockIdx.y;          // 0..1 : row group (64 b's)
  const int row0 = rg * 64;
  const int j0   = cg * 8;

  const int wave = tid >> 6;
  const int lane = tid & 63;
  const int col  = lane & 15;           // MFMA: A-row / B-row / C-col selector
  const int quad = lane >> 4;
  const int mrow = wave * 16 + col;     // this wave's A rows: wave*16 .. +15

  f32x4 acc0 = {0.f, 0.f, 0.f, 0.f};    // gate cols 0..15  (i, f for jj 0..7)
  f32x4 acc1 = {0.f, 0.f, 0.f, 0.f};    // gate cols 16..31 (g, o for jj 0..7)

  // B staging map (constant over k-loop): one 16B chunk per thread
  const int wrow = tid >> 3;            // 0..31 local gate-col
  const int kcB  = tid & 7;             // 0..7 k-chunk
  const int gB = wrow >> 3, jjB = wrow & 7;
  const unsigned short* wsrc =
      Wbf + (size_t)(gB * HID + j0 + jjB) * KDIM + kcB * 8;

  for (int kt = 0; kt < KDIM / 64; ++kt) {
    const int kbase = kt * 64;
    // ---- stage A tile: rows = batch, k<256 from x (f32, cast), else h (bf16)
    #pragma unroll
    for (int p = 0; p < 2; ++p) {
      int idx = p * 256 + tid;          // 512 chunks of 8 bf16
      int row = idx >> 3;
      int kc  = idx & 7;
      int k   = kbase + kc * 8;
      if (k < IN_DIM) {                 // uniform: kt<4 => whole tile from x
        const float* src = x_t + (size_t)(row0 + row) * IN_DIM + k;
        float4 f0 = *reinterpret_cast<const float4*>(src);
        float4 f1 = *reinterpret_cast<const float4*>(src + 4);
        ushort4 u0, u1;
        u0.x = f2bf(f0.x); u0.y = f2bf(f0.y); u0.z = f2bf(f0.z); u0.w = f2bf(f0.w);
        u1.x = f2bf(f1.x); u1.y = f2bf(f1.y); u1.z = f2bf(f1.z); u1.w = f2bf(f1.w);
        *reinterpret_cast<ushort4*>(&As[row][kc * 8])     = u0;
        *reinterpret_cast<ushort4*>(&As[row][kc * 8 + 4]) = u1;
      } else {
        const unsigned short* src = h_in + (size_t)(row0 + row) * HID + (k - IN_DIM);
        *reinterpret_cast<uint4*>(&As[row][kc * 8]) =
            *reinterpret_cast<const uint4*>(src);
      }
    }
    // ---- stage B tile (W rows, contiguous k)
    *reinterpret_cast<uint4*>(&Bs[wrow][kcB * 8]) =
        *reinterpret_cast<const uint4*>(wsrc + kbase);
    __syncthreads();

    // ---- MFMA: per wave, 2 k-steps x 2 n-tiles
    #pragma unroll
    for (int s = 0; s < 2; ++s) {
      bf16x8 a  = *reinterpret_cast<const bf16x8*>(&As[mrow][s * 32 + quad * 8]);
      bf16x8 b0 = *reinterpret_cast<const bf16x8*>(&Bs[col][s * 32 + quad * 8]);
      bf16x8 b1 = *reinterpret_cast<const bf16x8*>(&Bs[16 + col][s * 32 + quad * 8]);
      acc0 = __builtin_amdgcn_mfma_f32_16x16x32_bf16(a, b0, acc0, 0, 0, 0);
      acc1 = __builtin_amdgcn_mfma_f32_16x16x32_bf16(a, b1, acc1, 0, 0, 0);
    }
    __syncthreads();
  }

  // ---- spill accumulators to LDS (C/D layout: row=quad*4+r, col=lane&15)
  #pragma unroll
  for (int r = 0; r < 4; ++r) {
    Gs[wave * 16 + quad * 4 + r][col]      = acc0[r];
    Gs[wave * 16 + quad * 4 + r][16 + col] = acc1[r];
  }
  __syncthreads();

  // ---- epilogue: gather i,f,g,o per (b,j), LSTM cell update
  #pragma unroll
  for (int p = 0; p < 2; ++p) {
    int idx = p * 256 + tid;            // 512 = 64 rows x 8 j
    int row = idx >> 3;
    int jj  = idx & 7;
    float ig = Gs[row][jj]      + bsum[j0 + jj];
    float fg = Gs[row][8 + jj]  + bsum[HID + j0 + jj];
    float gg = Gs[row][16 + jj] + bsum[2 * HID + j0 + jj];
    float og = Gs[row][24 + jj] + bsum[3 * HID + j0 + jj];
    ig = 1.f / (1.f + __expf(-ig));
    fg = 1.f / (1.f + __expf(-fg));
    og = 1.f / (1.f + __expf(-og));
    gg = tanhf(gg);
    int b = row0 + row;
    int j = j0 + jj;
    size_t off = (size_t)b * HID + j;
    float c_old = c_ws[off];
    float c_new = fg * c_old + ig * gg;
    float h     = og * tanhf(c_new);
    c_ws[off]  = c_new;
    out_t[off] = h;
    h_out[off] = f2bf(h);
  }
}

__global__ void finalize(const float* __restrict__ c_ws, float* __restrict__ out) {
  int i = blockIdx.x * blockDim.x + threadIdx.x;
  if (i < BATCH * HID) {
    const size_t base = (size_t)T_STEPS * BATCH * HID;
    out[base + i] = out[(size_t)(T_STEPS - 1) * BATCH * HID + i];  // h_final
    out[base + BATCH * HID + i] = c_ws[i];                         // c_final
  }
}

extern "C" void kernel_launch(void* const* d_in, const int* in_sizes, int n_in,
                              void* d_out, int out_size, void* d_ws, size_t ws_size,
                              hipStream_t stream) {
  const float* x   = (const float*)d_in[0];
  const float* h0  = (const float*)d_in[1];
  const float* c0  = (const float*)d_in[2];
  const float* Wih = (const float*)d_in[3];
  const float* Whh = (const float*)d_in[4];
  const float* bih = (const float*)d_in[5];
  const float* bhh = (const float*)d_in[6];
  float* out = (float*)d_out;

  char* ws = (char*)d_ws;
  unsigned short* Wbf  = (unsigned short*)ws;                           // 10,485,760 B
  float*          bsum = (float*)(ws + 10485760);                       //     16,384 B
  unsigned short* hbf  = (unsigned short*)(ws + 10485760 + 16384);      //    524,288 B (x2 ping-pong)
  float*          cws  = (float*)(ws + 10485760 + 16384 + 524288);      //    524,288 B

  cast_weights<<<dim3((GATES * (KDIM / 4) + 255) / 256), 256, 0, stream>>>(Wih, Whh, Wbf);
  init_state<<<dim3((BATCH * HID + 255) / 256), 256, 0, stream>>>(h0, c0, bih, bhh,
                                                                  hbf, cws, bsum);
  for (int t = 0; t < T_STEPS; ++t) {
    lstm_step<<<dim3(128, 2), 256, 0, stream>>>(
        x + (size_t)t * BATCH * IN_DIM, Wbf, bsum,
        hbf + (size_t)(t & 1) * BATCH * HID,
        hbf + (size_t)((t + 1) & 1) * BATCH * HID,
        cws, out + (size_t)t * BATCH * HID);
  }
  finalize<<<dim3((BATCH * HID + 255) / 256), 256, 0, stream>>>(cws, out);
}